// Round 15
// baseline (60.385 us; speedup 1.0000x reference)
//
#include <hip/hip_runtime.h>
#include <hip/hip_bf16.h>

#define Bv 32
#define Cv 64
#define Nv 1024

typedef __attribute__((ext_vector_type(8))) short bf16x8;
typedef __attribute__((ext_vector_type(4))) float f32x4;
typedef __attribute__((ext_vector_type(8))) unsigned short us8;
typedef __attribute__((ext_vector_type(4))) unsigned short us4;

__device__ __forceinline__ float lrelu(float v) { return v >= 0.f ? v : 0.2f * v; }
// fast sigmoid: v_exp + v_rcp (no IEEE divide sequence); err ~1e-6 << bf16 ulp
__device__ __forceinline__ float sigmoidf_(float z) {
  return __builtin_amdgcn_rcpf(1.f + __expf(-z));
}
// HW-convert path (compiler pairs adjacent casts into v_cvt_pk_bf16_f32)
__device__ __forceinline__ unsigned short f2bh(float f) {
  __hip_bfloat16 h = __float2bfloat16(f);
  return reinterpret_cast<unsigned short&>(h);
}
__device__ __forceinline__ void gload16(const void* g, void* l) {
  __builtin_amdgcn_global_load_lds((const __attribute__((address_space(1))) void*)g,
                                   (__attribute__((address_space(3))) void*)l, 16, 0, 0);
}
// Counted-vmcnt pipeline primitives (T4): each wave waits for ITS OWN loads,
// then the raw barrier makes every wave's staged data visible to all.
__device__ __forceinline__ void wait_vm4() { asm volatile("s_waitcnt vmcnt(4)" ::: "memory"); }
__device__ __forceinline__ void wait_vm0() { asm volatile("s_waitcnt vmcnt(0)" ::: "memory"); }

// 64x64 bf16 tile, linear LDS dest, XOR-swizzled global source; granule g of
// row r holds global granule g ^ (r&7). fragr applies the same XOR on read.
__device__ __forceinline__ void stage_tile(const unsigned short* src, size_t stride,
                                           unsigned short* dst, int wave, int lane) {
#pragma unroll
  for (int p = 0; p < 2; ++p) {
    int q = wave * 2 + p;
    int rr = q * 8 + (lane >> 3);
    int gS = ((lane & 7) ^ (rr & 7)) << 3;
    gload16(&src[(size_t)rr * stride + gS], &dst[q * 512]);
  }
}
__device__ __forceinline__ bf16x8 fragr(const unsigned short* buf, int row, int ks, int lane) {
  return *reinterpret_cast<const bf16x8*>(
      &buf[row * 64 + (((ks * 4 + (lane >> 4)) ^ (row & 7)) << 3)]);
}

// ---------------------------------------------------------------------------
// prep: f32->bf16 conversions; x read ONCE (straight xb + transposed xbT).
// ---------------------------------------------------------------------------
__device__ __forceinline__ void cvt8(const float* in, unsigned short* out, int i) {
  const f32x4* p = reinterpret_cast<const f32x4*>(in + (size_t)i * 8);
  f32x4 a = p[0], b = p[1];
  us8 o;
  o[0] = f2bh(a[0]); o[1] = f2bh(a[1]); o[2] = f2bh(a[2]); o[3] = f2bh(a[3]);
  o[4] = f2bh(b[0]); o[5] = f2bh(b[1]); o[6] = f2bh(b[2]); o[7] = f2bh(b[3]);
  *reinterpret_cast<us8*>(out + (size_t)i * 8) = o;
}

__global__ __launch_bounds__(256)
void prep_kernel(const float* __restrict__ x, const float* __restrict__ Wsa,
                 const float* __restrict__ Wcm, const float* __restrict__ Wsw,
                 const float* __restrict__ Wdw, unsigned short* __restrict__ xb,
                 unsigned short* __restrict__ xbT, unsigned short* __restrict__ WsaB,
                 unsigned short* __restrict__ WcmB, unsigned short* __restrict__ WswB,
                 unsigned short* __restrict__ WdwB) {
  __shared__ unsigned short L[64 * 72];
  const int blk = blockIdx.x, tid = threadIdx.x;
  if (blk < 512) {
    int b = blk >> 4, n0 = (blk & 15) * 64;
    int c = tid >> 2, nseg = (tid & 3) * 16;
    const float* src = &x[((size_t)(b * 64 + c) << 10) + n0 + nseg];
    unsigned short v16[16];
#pragma unroll
    for (int q = 0; q < 4; ++q) {
      f32x4 v = *reinterpret_cast<const f32x4*>(src + q * 4);
#pragma unroll
      for (int e = 0; e < 4; ++e) {
        unsigned short bf = f2bh(v[e]);
        v16[q * 4 + e] = bf;
        L[(nseg + q * 4 + e) * 72 + c] = bf;
      }
    }
    unsigned short* sd = &xb[((size_t)(b * 64 + c) << 10) + n0 + nseg];
    *reinterpret_cast<us8*>(sd) = *reinterpret_cast<const us8*>(&v16[0]);
    *reinterpret_cast<us8*>(sd + 8) = *reinterpret_cast<const us8*>(&v16[8]);
    __syncthreads();
    int n = tid >> 2, cs = (tid & 3) * 16;
    us8 a = *reinterpret_cast<const us8*>(&L[n * 72 + cs]);
    us8 bq = *reinterpret_cast<const us8*>(&L[n * 72 + cs + 8]);
    unsigned short* dst = &xbT[(((size_t)b << 10) + n0 + n) * 64 + cs];
    *reinterpret_cast<us8*>(dst) = a;
    *reinterpret_cast<us8*>(dst + 8) = bq;
  } else if (blk < 1024) {
    cvt8(Wsa, WsaB, (blk - 512) * 256 + tid);
  } else if (blk < 1056) {
    cvt8(Wcm, WcmB, (blk - 1024) * 256 + tid);
  } else if (blk < 1058) {
    cvt8(Wsw, WswB, (blk - 1056) * 256 + tid);
  } else {
    cvt8(Wdw, WdwB, (blk - 1058) * 256 + tid);
  }
}

// ---------------------------------------------------------------------------
// k1x1: fused  t = lrelu(x @ Wsa^T)  ->  x1 = x + lrelu(Wsw @ t + bsw)
// (R10/R11 structure — best measured)
// ---------------------------------------------------------------------------
__global__ __launch_bounds__(256)
void k1x1_kernel(const unsigned short* __restrict__ xb,
                 const unsigned short* __restrict__ WsaB,
                 const unsigned short* __restrict__ WswB,
                 const float* __restrict__ x, const float* __restrict__ bsw,
                 unsigned short* __restrict__ x1b, float* __restrict__ en) {
  __shared__ __align__(16) unsigned short As[2][4096];
  __shared__ __align__(16) unsigned short Bs[2][4096];
  __shared__ __align__(16) unsigned short TT[64 * 72];
  __shared__ __align__(16) float Xres[64 * 68];
  const int tid = threadIdx.x, wave = tid >> 6, lane = tid & 63;
  const int b = blockIdx.y, col0 = blockIdx.x * 64, row0 = b * 64;
  const int wr = wave >> 1, wc = wave & 1;
  const bool doEn = (blockIdx.x == 0);
  f32x4 acc[2][2], accE[4];
#pragma unroll
  for (int i = 0; i < 2; ++i)
#pragma unroll
    for (int j = 0; j < 2; ++j) acc[i][j] = (f32x4){0.f, 0.f, 0.f, 0.f};
#pragma unroll
  for (int j = 0; j < 4; ++j) accE[j] = (f32x4){0.f, 0.f, 0.f, 0.f};

  stage_tile(&xb[(size_t)row0 * Nv], Nv, As[0], wave, lane);
  stage_tile(&WsaB[(size_t)col0 * Nv], Nv, Bs[0], wave, lane);
  __syncthreads();
  for (int t = 0; t < 16; ++t) {
    const int cur = t & 1;
    if (t < 15) {
      stage_tile(&xb[(size_t)row0 * Nv + (t + 1) * 64], Nv, As[cur ^ 1], wave, lane);
      stage_tile(&WsaB[(size_t)col0 * Nv + (t + 1) * 64], Nv, Bs[cur ^ 1], wave, lane);
    }
#pragma unroll
    for (int ks = 0; ks < 2; ++ks) {
      bf16x8 af[2], bfg[2];
#pragma unroll
      for (int i = 0; i < 2; ++i) af[i] = fragr(As[cur], wr * 32 + i * 16 + (lane & 15), ks, lane);
#pragma unroll
      for (int j = 0; j < 2; ++j) bfg[j] = fragr(Bs[cur], wc * 32 + j * 16 + (lane & 15), ks, lane);
#pragma unroll
      for (int i = 0; i < 2; ++i)
#pragma unroll
        for (int j = 0; j < 2; ++j)
          acc[i][j] = __builtin_amdgcn_mfma_f32_16x16x32_bf16(af[i], bfg[j], acc[i][j], 0, 0, 0);
      if (doEn) {
        bf16x8 aE = fragr(As[cur], wave * 16 + (lane & 15), ks, lane);
#pragma unroll
        for (int j = 0; j < 4; ++j) {
          bf16x8 bE = fragr(As[cur], j * 16 + (lane & 15), ks, lane);
          accE[j] = __builtin_amdgcn_mfma_f32_16x16x32_bf16(aE, bE, accE[j], 0, 0, 0);
        }
      }
    }
    __syncthreads();
  }
#pragma unroll
  for (int i = 0; i < 2; ++i)
#pragma unroll
    for (int j = 0; j < 2; ++j) {
      us4 tv;
#pragma unroll
      for (int r = 0; r < 4; ++r) tv[r] = f2bh(lrelu(acc[i][j][r]));
      *reinterpret_cast<us4*>(
          &TT[(wc * 32 + j * 16 + (lane & 15)) * 72 + wr * 32 + i * 16 + (lane >> 4) * 4]) = tv;
    }
  {
    int o = tid >> 2, ms = (tid & 3) * 16;
    const float* xs = &x[((size_t)(row0 + o) << 10) + col0 + ms];
#pragma unroll
    for (int q = 0; q < 4; ++q)
      *reinterpret_cast<f32x4*>(&Xres[o * 68 + ms + q * 4]) =
          *reinterpret_cast<const f32x4*>(xs + q * 4);
  }
  if (doEn) {
#pragma unroll
    for (int j = 0; j < 4; ++j)
#pragma unroll
      for (int r = 0; r < 4; ++r)
        en[(size_t)b * 4096 + (wave * 16 + (lane >> 4) * 4 + r) * 64 + j * 16 + (lane & 15)] =
            accE[j][r];
  }
  __syncthreads();
  bf16x8 afw[2];
#pragma unroll
  for (int ks = 0; ks < 2; ++ks)
    afw[ks] = *reinterpret_cast<const bf16x8*>(
        &WswB[(wave * 16 + (lane & 15)) * 64 + ks * 32 + (lane >> 4) * 8]);
  f32x4 acc2[4];
#pragma unroll
  for (int j = 0; j < 4; ++j) acc2[j] = (f32x4){0.f, 0.f, 0.f, 0.f};
#pragma unroll
  for (int ks = 0; ks < 2; ++ks)
#pragma unroll
    for (int j = 0; j < 4; ++j) {
      bf16x8 bfr = *reinterpret_cast<const bf16x8*>(
          &TT[(j * 16 + (lane & 15)) * 72 + ks * 32 + (lane >> 4) * 8]);
      acc2[j] = __builtin_amdgcn_mfma_f32_16x16x32_bf16(afw[ks], bfr, acc2[j], 0, 0, 0);
    }
  f32x4 bs4 = *reinterpret_cast<const f32x4*>(&bsw[wave * 16 + (lane >> 4) * 4]);
#pragma unroll
  for (int j = 0; j < 4; ++j)
#pragma unroll
    for (int r = 0; r < 4; ++r) {
      int o = wave * 16 + (lane >> 4) * 4 + r;
      int nl = j * 16 + (lane & 15);
      x1b[((size_t)(row0 + o) << 10) + col0 + nl] =
          f2bh(Xres[o * 68 + nl] + lrelu(acc2[j][r] + bs4[r]));
    }
}

// ---------------------------------------------------------------------------
// bn_att: attention = BN(rowmax(en) - en), bf16 out. (1 wave/channel)
// ---------------------------------------------------------------------------
__global__ __launch_bounds__(64)
void bn_att_kernel(const float* __restrict__ en, const float* __restrict__ bng,
                   const float* __restrict__ bnb, unsigned short* __restrict__ att) {
  const int c = blockIdx.x, d = threadIdx.x;
  float v[Bv];
  float sum = 0.f, sumsq = 0.f;
#pragma unroll
  for (int b = 0; b < Bv; ++b) {
    float e = en[(size_t)b * 4096 + c * 64 + d];
    float m = e;
#pragma unroll
    for (int o = 32; o > 0; o >>= 1) m = fmaxf(m, __shfl_xor(m, o));
    v[b] = m - e;
    sum += v[b]; sumsq += v[b] * v[b];
  }
#pragma unroll
  for (int o = 32; o > 0; o >>= 1) { sum += __shfl_xor(sum, o); sumsq += __shfl_xor(sumsq, o); }
  const float inv = 1.f / (float)(Bv * Cv);
  float mu = sum * inv;
  float var = sumsq * inv - mu * mu;
  float rs = rsqrtf(var + 1e-5f);
  float g = bng[c], be = bnb[c];
#pragma unroll
  for (int b = 0; b < Bv; ++b)
    att[(size_t)b * 4096 + c * 64 + d] = f2bh(g * (v[b] - mu) * rs + be);
}

// ---------------------------------------------------------------------------
// dynmega: R10 chunk body; ONE lever = 3-buffer counted-vmcnt pipeline:
// per chunk {vmcnt(4): own ch-loads done -> s_barrier: all waves' ch data
// visible, prior readers of slot (ch+2)%3 retired -> issue ch+2 -> compute}.
// Prefetched loads stay in flight ACROSS barriers (never drained to 0 until
// the tail). LDS: XG 9K + buf 48K + SBt 9K = 66K (grid-limited 2 blocks/CU).
// ---------------------------------------------------------------------------
__global__ __launch_bounds__(256)
void dynmega_kernel(const unsigned short* __restrict__ xbT,
                    const unsigned short* __restrict__ x1b,
                    const unsigned short* __restrict__ attB,
                    const unsigned short* __restrict__ WcmB,
                    const unsigned short* __restrict__ WdwB,
                    const float* __restrict__ x, const float* __restrict__ bcm,
                    const float* __restrict__ bdw, const float* __restrict__ gamma_p,
                    float* __restrict__ dout) {
  __shared__ __align__(16) unsigned short XG[64 * 72];
  __shared__ __align__(16) char buf[49152];  // 3 x 16KB {WT 8KB, X1 8KB}
  __shared__ __align__(16) unsigned short SBt[4 * 16 * 72];
  const int tid = threadIdx.x, wave = tid >> 6, lane = tid & 63;
  const int m0 = blockIdx.x * 64, b = blockIdx.y;
  // ---- head: xglb tile -> XG ----
  {
    unsigned short* XB = (unsigned short*)buf;
    float* Xr = (float*)(buf + 8192);
    stage_tile(&xbT[((size_t)b * 1024 + m0) * 64], 64, XB, wave, lane);
    {
      int o = tid >> 2, ms = (tid & 3) * 16;
      const float* xs = &x[((size_t)(b * 64 + o) << 10) + m0 + ms];
#pragma unroll
      for (int q = 0; q < 4; ++q)
        *reinterpret_cast<f32x4*>(&Xr[o * 68 + ms + q * 4]) =
            *reinterpret_cast<const f32x4*>(xs + q * 4);
    }
    __syncthreads();
    bf16x8 afA[2];
#pragma unroll
    for (int ks = 0; ks < 2; ++ks)
      afA[ks] = *reinterpret_cast<const bf16x8*>(
          &attB[(size_t)b * 4096 + (wave * 16 + (lane & 15)) * 64 + ks * 32 + (lane >> 4) * 8]);
    const float g0 = gamma_p[0];
#pragma unroll
    for (int j = 0; j < 4; ++j) {
      f32x4 ah = (f32x4){0.f, 0.f, 0.f, 0.f};
#pragma unroll
      for (int ks = 0; ks < 2; ++ks) {
        bf16x8 bfh = fragr(XB, j * 16 + (lane & 15), ks, lane);
        ah = __builtin_amdgcn_mfma_f32_16x16x32_bf16(afA[ks], bfh, ah, 0, 0, 0);
      }
      us4 gv;
#pragma unroll
      for (int r = 0; r < 4; ++r)
        gv[r] =
            f2bh(g0 * ah[r] + Xr[(wave * 16 + (lane >> 4) * 4 + r) * 68 + j * 16 + (lane & 15)]);
      *reinterpret_cast<us4*>(
          &XG[(j * 16 + (lane & 15)) * 72 + wave * 16 + (lane >> 4) * 4]) = gv;
    }
  }
  __syncthreads();  // XG ready; buf free; all vmem drained (clean pipeline state)
  bf16x8 xgf[2];
#pragma unroll
  for (int ks = 0; ks < 2; ++ks)
    xgf[ks] = *reinterpret_cast<const bf16x8*>(
        &XG[(wave * 16 + (lane & 15)) * 72 + ks * 32 + (lane >> 4) * 8]);
  f32x4 accy[4];
#pragma unroll
  for (int j = 0; j < 4; ++j) accy[j] = (f32x4){0.f, 0.f, 0.f, 0.f};
  unsigned short* SB = &SBt[wave * 16 * 72];

  auto stage_chunk = [&](int ch, char* slot) {
    stage_tile(&WcmB[(size_t)ch * 4096], 64, (unsigned short*)slot, wave, lane);
    stage_tile(&x1b[(size_t)b * 65536 + ch * 64], 1024, (unsigned short*)(slot + 8192), wave,
               lane);
  };
  auto chunk_body = [&](const char* base, int ch) {
    const unsigned short* WTcur = (const unsigned short*)base;
    const unsigned short* X1cur = (const unsigned short*)(base + 8192);
#pragma unroll
    for (int i = 0; i < 4; ++i) {
      f32x4 s = (f32x4){0.f, 0.f, 0.f, 0.f};
#pragma unroll
      for (int ks = 0; ks < 2; ++ks) {
        bf16x8 af = fragr(WTcur, i * 16 + (lane & 15), ks, lane);
        s = __builtin_amdgcn_mfma_f32_16x16x32_bf16(af, xgf[ks], s, 0, 0, 0);
      }
      f32x4 bc4 = *reinterpret_cast<const f32x4*>(&bcm[ch * 64 + i * 16 + (lane >> 4) * 4]);
      us4 sv;
#pragma unroll
      for (int r = 0; r < 4; ++r) sv[r] = f2bh(sigmoidf_(s[r] + bc4[r]));
      *reinterpret_cast<us4*>(&SB[(lane & 15) * 72 + i * 16 + (lane >> 4) * 4]) = sv;
    }
#pragma unroll
    for (int ks = 0; ks < 2; ++ks) {
      bf16x8 b2 = *reinterpret_cast<const bf16x8*>(
          &SB[(lane & 15) * 72 + ks * 32 + (lane >> 4) * 8]);
#pragma unroll
      for (int jc = 0; jc < 4; ++jc) {
        bf16x8 a2 = fragr(X1cur, jc * 16 + (lane & 15), ks, lane);
        accy[jc] = __builtin_amdgcn_mfma_f32_16x16x32_bf16(a2, b2, accy[jc], 0, 0, 0);
      }
    }
  };
  auto pipe_iter = [&](int ch, int curslot, int nxtslot) {
    if (ch < 15) wait_vm4(); else wait_vm0();
    __builtin_amdgcn_s_barrier();
    if (ch + 2 <= 15) stage_chunk(ch + 2, buf + nxtslot * 16384);
    chunk_body(buf + curslot * 16384, ch);
  };

  // prologue: ch0 -> slot0, ch1 -> slot1 (8 loads/wave in flight)
  stage_chunk(0, buf);
  stage_chunk(1, buf + 16384);
#pragma unroll
  for (int g = 0; g < 5; ++g) {
    pipe_iter(3 * g + 0, 0, 2);
    pipe_iter(3 * g + 1, 1, 0);
    pipe_iter(3 * g + 2, 2, 1);
  }
  pipe_iter(15, 0, 2);  // 15 % 3 == 0; no further issues

  // epilogue (wave-private SB reuse): y1 = lrelu(accy) -> YT; out = lrelu(Wdw@y1+bdw)
  unsigned short* YT = SB;
#pragma unroll
  for (int jc = 0; jc < 4; ++jc) {
    us4 yv;
#pragma unroll
    for (int r = 0; r < 4; ++r) yv[r] = f2bh(lrelu(accy[jc][r]));
    *reinterpret_cast<us4*>(&YT[(lane & 15) * 72 + jc * 16 + (lane >> 4) * 4]) = yv;
  }
  bf16x8 afW[4][2];
#pragma unroll
  for (int jo = 0; jo < 4; ++jo)
#pragma unroll
    for (int ks = 0; ks < 2; ++ks)
      afW[jo][ks] = *reinterpret_cast<const bf16x8*>(
          &WdwB[(jo * 16 + (lane & 15)) * 64 + ks * 32 + (lane >> 4) * 8]);
  f32x4 accf[4];
#pragma unroll
  for (int j = 0; j < 4; ++j) accf[j] = (f32x4){0.f, 0.f, 0.f, 0.f};
#pragma unroll
  for (int ks = 0; ks < 2; ++ks) {
    bf16x8 yf = *reinterpret_cast<const bf16x8*>(
        &YT[(lane & 15) * 72 + ks * 32 + (lane >> 4) * 8]);
#pragma unroll
    for (int jo = 0; jo < 4; ++jo)
      accf[jo] = __builtin_amdgcn_mfma_f32_16x16x32_bf16(afW[jo][ks], yf, accf[jo], 0, 0, 0);
  }
#pragma unroll
  for (int jo = 0; jo < 4; ++jo) {
    f32x4 bs4 = *reinterpret_cast<const f32x4*>(&bdw[jo * 16 + (lane >> 4) * 4]);
#pragma unroll
    for (int r = 0; r < 4; ++r) {
      int o = jo * 16 + (lane >> 4) * 4 + r;
      dout[((size_t)(b * 64 + o) << 10) + m0 + wave * 16 + (lane & 15)] =
          lrelu(accf[jo][r] + bs4[r]);
    }
  }
}

extern "C" void kernel_launch(void* const* d_in, const int* in_sizes, int n_in,
                              void* d_out, int out_size, void* d_ws, size_t ws_size,
                              hipStream_t stream) {
  const float* x     = (const float*)d_in[0];
  const float* W_sa  = (const float*)d_in[1];
  const float* W_sw  = (const float*)d_in[2];
  const float* b_sw  = (const float*)d_in[3];
  const float* bn_g  = (const float*)d_in[4];
  const float* bn_b  = (const float*)d_in[5];
  const float* gamma = (const float*)d_in[6];
  const float* W_cm  = (const float*)d_in[7];
  const float* b_cm  = (const float*)d_in[8];
  const float* W_dw  = (const float*)d_in[9];
  const float* b_dw  = (const float*)d_in[10];
  float* out = (float*)d_out;

  char* ws = (char*)d_ws;
  const size_t MB = 1024 * 1024;
  unsigned short* xb     = (unsigned short*)(ws + 0 * MB);    // 4MB
  unsigned short* xbT    = (unsigned short*)(ws + 4 * MB);    // 4MB
  unsigned short* WsaB   = (unsigned short*)(ws + 8 * MB);    // 2MB
  unsigned short* WcmB   = (unsigned short*)(ws + 10 * MB);   // 128KB
  unsigned short* WswB   = (unsigned short*)(ws + 10 * MB + 256 * 1024);  // 8KB
  unsigned short* WdwB   = (unsigned short*)(ws + 10 * MB + 288 * 1024);  // 8KB
  unsigned short* x1b    = (unsigned short*)(ws + 11 * MB);   // 4MB
  float*          en     = (float*)(ws + 15 * MB);            // 512KB
  unsigned short* attB   = (unsigned short*)(ws + 16 * MB);   // 256KB

  prep_kernel<<<1060, 256, 0, stream>>>(x, W_sa, W_cm, W_sw, W_dw, xb, xbT, WsaB, WcmB, WswB,
                                        WdwB);
  k1x1_kernel<<<dim3(16, Bv), 256, 0, stream>>>(xb, WsaB, WswB, x, b_sw, x1b, en);
  bn_att_kernel<<<Cv, 64, 0, stream>>>(en, bn_g, bn_b, attB);
  dynmega_kernel<<<dim3(16, Bv), 256, 0, stream>>>(xbT, x1b, attB, WcmB, WdwB, x, b_cm, b_dw,
                                                   gamma, out);
}

// Round 16
// 58.740 us; speedup vs baseline: 1.0280x; 1.0280x over previous
//
#include <hip/hip_runtime.h>
#include <hip/hip_bf16.h>

#define Bv 32
#define Cv 64
#define Nv 1024

typedef __attribute__((ext_vector_type(8))) short bf16x8;
typedef __attribute__((ext_vector_type(4))) float f32x4;
typedef __attribute__((ext_vector_type(8))) unsigned short us8;
typedef __attribute__((ext_vector_type(4))) unsigned short us4;

__device__ __forceinline__ float lrelu(float v) { return v >= 0.f ? v : 0.2f * v; }
// fast sigmoid: v_exp + v_rcp (no IEEE divide sequence); err ~1e-6 << bf16 ulp
__device__ __forceinline__ float sigmoidf_(float z) {
  return __builtin_amdgcn_rcpf(1.f + __expf(-z));
}
// HW-convert path (compiler pairs adjacent casts into v_cvt_pk_bf16_f32)
__device__ __forceinline__ unsigned short f2bh(float f) {
  __hip_bfloat16 h = __float2bfloat16(f);
  return reinterpret_cast<unsigned short&>(h);
}
__device__ __forceinline__ void gload16(const void* g, void* l) {
  __builtin_amdgcn_global_load_lds((const __attribute__((address_space(1))) void*)g,
                                   (__attribute__((address_space(3))) void*)l, 16, 0, 0);
}
// 64x64 bf16 tile, linear LDS dest, XOR-swizzled global source; granule g of
// row r holds global granule g ^ (r&7). fragr applies the same XOR on read.
__device__ __forceinline__ void stage_tile(const unsigned short* src, size_t stride,
                                           unsigned short* dst, int wave, int lane) {
#pragma unroll
  for (int p = 0; p < 2; ++p) {
    int q = wave * 2 + p;
    int rr = q * 8 + (lane >> 3);
    int gS = ((lane & 7) ^ (rr & 7)) << 3;
    gload16(&src[(size_t)rr * stride + gS], &dst[q * 512]);
  }
}
__device__ __forceinline__ bf16x8 fragr(const unsigned short* buf, int row, int ks, int lane) {
  return *reinterpret_cast<const bf16x8*>(
      &buf[row * 64 + (((ks * 4 + (lane >> 4)) ^ (row & 7)) << 3)]);
}

// ---------------------------------------------------------------------------
// prep: f32->bf16 conversions; x read ONCE (straight xb + transposed xbT).
// ---------------------------------------------------------------------------
__device__ __forceinline__ void cvt8(const float* in, unsigned short* out, int i) {
  const f32x4* p = reinterpret_cast<const f32x4*>(in + (size_t)i * 8);
  f32x4 a = p[0], b = p[1];
  us8 o;
  o[0] = f2bh(a[0]); o[1] = f2bh(a[1]); o[2] = f2bh(a[2]); o[3] = f2bh(a[3]);
  o[4] = f2bh(b[0]); o[5] = f2bh(b[1]); o[6] = f2bh(b[2]); o[7] = f2bh(b[3]);
  *reinterpret_cast<us8*>(out + (size_t)i * 8) = o;
}

__global__ __launch_bounds__(256)
void prep_kernel(const float* __restrict__ x, const float* __restrict__ Wsa,
                 const float* __restrict__ Wcm, const float* __restrict__ Wsw,
                 const float* __restrict__ Wdw, unsigned short* __restrict__ xb,
                 unsigned short* __restrict__ xbT, unsigned short* __restrict__ WsaB,
                 unsigned short* __restrict__ WcmB, unsigned short* __restrict__ WswB,
                 unsigned short* __restrict__ WdwB) {
  __shared__ unsigned short L[64 * 72];
  const int blk = blockIdx.x, tid = threadIdx.x;
  if (blk < 512) {
    int b = blk >> 4, n0 = (blk & 15) * 64;
    int c = tid >> 2, nseg = (tid & 3) * 16;
    const float* src = &x[((size_t)(b * 64 + c) << 10) + n0 + nseg];
    unsigned short v16[16];
#pragma unroll
    for (int q = 0; q < 4; ++q) {
      f32x4 v = *reinterpret_cast<const f32x4*>(src + q * 4);
#pragma unroll
      for (int e = 0; e < 4; ++e) {
        unsigned short bf = f2bh(v[e]);
        v16[q * 4 + e] = bf;
        L[(nseg + q * 4 + e) * 72 + c] = bf;
      }
    }
    // straight xb: 32B contiguous per thread
    unsigned short* sd = &xb[((size_t)(b * 64 + c) << 10) + n0 + nseg];
    *reinterpret_cast<us8*>(sd) = *reinterpret_cast<const us8*>(&v16[0]);
    *reinterpret_cast<us8*>(sd + 8) = *reinterpret_cast<const us8*>(&v16[8]);
    __syncthreads();
    int n = tid >> 2, cs = (tid & 3) * 16;
    us8 a = *reinterpret_cast<const us8*>(&L[n * 72 + cs]);
    us8 bq = *reinterpret_cast<const us8*>(&L[n * 72 + cs + 8]);
    unsigned short* dst = &xbT[(((size_t)b << 10) + n0 + n) * 64 + cs];
    *reinterpret_cast<us8*>(dst) = a;
    *reinterpret_cast<us8*>(dst + 8) = bq;
  } else if (blk < 1024) {
    cvt8(Wsa, WsaB, (blk - 512) * 256 + tid);
  } else if (blk < 1056) {
    cvt8(Wcm, WcmB, (blk - 1024) * 256 + tid);
  } else if (blk < 1058) {
    cvt8(Wsw, WswB, (blk - 1056) * 256 + tid);
  } else {
    cvt8(Wdw, WdwB, (blk - 1058) * 256 + tid);
  }
}

// ---------------------------------------------------------------------------
// k1x1: fused  t = lrelu(x @ Wsa^T)  ->  x1 = x + lrelu(Wsw @ t + bsw)
// (R10 structure; epilogue uses HW cvt)
// ---------------------------------------------------------------------------
__global__ __launch_bounds__(256)
void k1x1_kernel(const unsigned short* __restrict__ xb,
                 const unsigned short* __restrict__ WsaB,
                 const unsigned short* __restrict__ WswB,
                 const float* __restrict__ x, const float* __restrict__ bsw,
                 unsigned short* __restrict__ x1b, float* __restrict__ en) {
  __shared__ __align__(16) unsigned short As[2][4096];
  __shared__ __align__(16) unsigned short Bs[2][4096];
  __shared__ __align__(16) unsigned short TT[64 * 72];
  __shared__ __align__(16) float Xres[64 * 68];
  const int tid = threadIdx.x, wave = tid >> 6, lane = tid & 63;
  const int b = blockIdx.y, col0 = blockIdx.x * 64, row0 = b * 64;
  const int wr = wave >> 1, wc = wave & 1;
  const bool doEn = (blockIdx.x == 0);
  f32x4 acc[2][2], accE[4];
#pragma unroll
  for (int i = 0; i < 2; ++i)
#pragma unroll
    for (int j = 0; j < 2; ++j) acc[i][j] = (f32x4){0.f, 0.f, 0.f, 0.f};
#pragma unroll
  for (int j = 0; j < 4; ++j) accE[j] = (f32x4){0.f, 0.f, 0.f, 0.f};

  stage_tile(&xb[(size_t)row0 * Nv], Nv, As[0], wave, lane);
  stage_tile(&WsaB[(size_t)col0 * Nv], Nv, Bs[0], wave, lane);
  __syncthreads();
  for (int t = 0; t < 16; ++t) {
    const int cur = t & 1;
    if (t < 15) {
      stage_tile(&xb[(size_t)row0 * Nv + (t + 1) * 64], Nv, As[cur ^ 1], wave, lane);
      stage_tile(&WsaB[(size_t)col0 * Nv + (t + 1) * 64], Nv, Bs[cur ^ 1], wave, lane);
    }
#pragma unroll
    for (int ks = 0; ks < 2; ++ks) {
      bf16x8 af[2], bfg[2];
#pragma unroll
      for (int i = 0; i < 2; ++i) af[i] = fragr(As[cur], wr * 32 + i * 16 + (lane & 15), ks, lane);
#pragma unroll
      for (int j = 0; j < 2; ++j) bfg[j] = fragr(Bs[cur], wc * 32 + j * 16 + (lane & 15), ks, lane);
#pragma unroll
      for (int i = 0; i < 2; ++i)
#pragma unroll
        for (int j = 0; j < 2; ++j)
          acc[i][j] = __builtin_amdgcn_mfma_f32_16x16x32_bf16(af[i], bfg[j], acc[i][j], 0, 0, 0);
      if (doEn) {
        bf16x8 aE = fragr(As[cur], wave * 16 + (lane & 15), ks, lane);
#pragma unroll
        for (int j = 0; j < 4; ++j) {
          bf16x8 bE = fragr(As[cur], j * 16 + (lane & 15), ks, lane);
          accE[j] = __builtin_amdgcn_mfma_f32_16x16x32_bf16(aE, bE, accE[j], 0, 0, 0);
        }
      }
    }
    __syncthreads();
  }
  // t-tile -> TT [n][c]
#pragma unroll
  for (int i = 0; i < 2; ++i)
#pragma unroll
    for (int j = 0; j < 2; ++j) {
      us4 tv;
#pragma unroll
      for (int r = 0; r < 4; ++r) tv[r] = f2bh(lrelu(acc[i][j][r]));
      *reinterpret_cast<us4*>(
          &TT[(wc * 32 + j * 16 + (lane & 15)) * 72 + wr * 32 + i * 16 + (lane >> 4) * 4]) = tv;
    }
  {  // residual x tile [o][n]
    int o = tid >> 2, ms = (tid & 3) * 16;
    const float* xs = &x[((size_t)(row0 + o) << 10) + col0 + ms];
#pragma unroll
    for (int q = 0; q < 4; ++q)
      *reinterpret_cast<f32x4*>(&Xres[o * 68 + ms + q * 4]) =
          *reinterpret_cast<const f32x4*>(xs + q * 4);
  }
  if (doEn) {
#pragma unroll
    for (int j = 0; j < 4; ++j)
#pragma unroll
      for (int r = 0; r < 4; ++r)
        en[(size_t)b * 4096 + (wave * 16 + (lane >> 4) * 4 + r) * 64 + j * 16 + (lane & 15)] =
            accE[j][r];
  }
  __syncthreads();
  // chanmix: x1[o][n] = x + lrelu(Wsw @ t + bsw)
  bf16x8 afw[2];
#pragma unroll
  for (int ks = 0; ks < 2; ++ks)
    afw[ks] = *reinterpret_cast<const bf16x8*>(
        &WswB[(wave * 16 + (lane & 15)) * 64 + ks * 32 + (lane >> 4) * 8]);
  f32x4 acc2[4];
#pragma unroll
  for (int j = 0; j < 4; ++j) acc2[j] = (f32x4){0.f, 0.f, 0.f, 0.f};
#pragma unroll
  for (int ks = 0; ks < 2; ++ks)
#pragma unroll
    for (int j = 0; j < 4; ++j) {
      bf16x8 bfr = *reinterpret_cast<const bf16x8*>(
          &TT[(j * 16 + (lane & 15)) * 72 + ks * 32 + (lane >> 4) * 8]);
      acc2[j] = __builtin_amdgcn_mfma_f32_16x16x32_bf16(afw[ks], bfr, acc2[j], 0, 0, 0);
    }
  f32x4 bs4 = *reinterpret_cast<const f32x4*>(&bsw[wave * 16 + (lane >> 4) * 4]);
#pragma unroll
  for (int j = 0; j < 4; ++j)
#pragma unroll
    for (int r = 0; r < 4; ++r) {
      int o = wave * 16 + (lane >> 4) * 4 + r;
      int nl = j * 16 + (lane & 15);
      x1b[((size_t)(row0 + o) << 10) + col0 + nl] =
          f2bh(Xres[o * 68 + nl] + lrelu(acc2[j][r] + bs4[r]));
    }
}

// ---------------------------------------------------------------------------
// bn_att: attention = BN(rowmax(en) - en), bf16 out. (1 wave/channel)
// ---------------------------------------------------------------------------
__global__ __launch_bounds__(64)
void bn_att_kernel(const float* __restrict__ en, const float* __restrict__ bng,
                   const float* __restrict__ bnb, unsigned short* __restrict__ att) {
  const int c = blockIdx.x, d = threadIdx.x;
  float v[Bv];
  float sum = 0.f, sumsq = 0.f;
#pragma unroll
  for (int b = 0; b < Bv; ++b) {
    float e = en[(size_t)b * 4096 + c * 64 + d];
    float m = e;
#pragma unroll
    for (int o = 32; o > 0; o >>= 1) m = fmaxf(m, __shfl_xor(m, o));
    v[b] = m - e;
    sum += v[b]; sumsq += v[b] * v[b];
  }
#pragma unroll
  for (int o = 32; o > 0; o >>= 1) { sum += __shfl_xor(sum, o); sumsq += __shfl_xor(sumsq, o); }
  const float inv = 1.f / (float)(Bv * Cv);
  float mu = sum * inv;
  float var = sumsq * inv - mu * mu;
  float rs = rsqrtf(var + 1e-5f);
  float g = bng[c], be = bnb[c];
#pragma unroll
  for (int b = 0; b < Bv; ++b)
    att[(size_t)b * 4096 + c * 64 + d] = f2bh(g * (v[b] - mu) * rs + be);
}

// ---------------------------------------------------------------------------
// dynmega: R10-exact (best measured): rcp-sigmoid, cvt_pk packs, x2-unrolled.
// ---------------------------------------------------------------------------
__global__ __launch_bounds__(256)
void dynmega_kernel(const unsigned short* __restrict__ xbT,
                    const unsigned short* __restrict__ x1b,
                    const unsigned short* __restrict__ attB,
                    const unsigned short* __restrict__ WcmB,
                    const unsigned short* __restrict__ WdwB,
                    const float* __restrict__ x, const float* __restrict__ bcm,
                    const float* __restrict__ bdw, const float* __restrict__ gamma_p,
                    float* __restrict__ dout) {
  __shared__ __align__(16) unsigned short XG[64 * 72];
  __shared__ __align__(16) char buf[32768];  // 2 x 16KB {WT 8KB, X1 8KB}
  __shared__ __align__(16) unsigned short SBt[4 * 16 * 72];
  const int tid = threadIdx.x, wave = tid >> 6, lane = tid & 63;
  const int m0 = blockIdx.x * 64, b = blockIdx.y;
  // ---- head: xglb tile -> XG ----
  {
    unsigned short* XB = (unsigned short*)buf;
    float* Xr = (float*)(buf + 8192);
    stage_tile(&xbT[((size_t)b * 1024 + m0) * 64], 64, XB, wave, lane);
    {
      int o = tid >> 2, ms = (tid & 3) * 16;
      const float* xs = &x[((size_t)(b * 64 + o) << 10) + m0 + ms];
#pragma unroll
      for (int q = 0; q < 4; ++q)
        *reinterpret_cast<f32x4*>(&Xr[o * 68 + ms + q * 4]) =
            *reinterpret_cast<const f32x4*>(xs + q * 4);
    }
    __syncthreads();
    bf16x8 afA[2];
#pragma unroll
    for (int ks = 0; ks < 2; ++ks)
      afA[ks] = *reinterpret_cast<const bf16x8*>(
          &attB[(size_t)b * 4096 + (wave * 16 + (lane & 15)) * 64 + ks * 32 + (lane >> 4) * 8]);
    const float g0 = gamma_p[0];
#pragma unroll
    for (int j = 0; j < 4; ++j) {
      f32x4 ah = (f32x4){0.f, 0.f, 0.f, 0.f};
#pragma unroll
      for (int ks = 0; ks < 2; ++ks) {
        bf16x8 bfh = fragr(XB, j * 16 + (lane & 15), ks, lane);
        ah = __builtin_amdgcn_mfma_f32_16x16x32_bf16(afA[ks], bfh, ah, 0, 0, 0);
      }
      us4 gv;
#pragma unroll
      for (int r = 0; r < 4; ++r)
        gv[r] =
            f2bh(g0 * ah[r] + Xr[(wave * 16 + (lane >> 4) * 4 + r) * 68 + j * 16 + (lane & 15)]);
      *reinterpret_cast<us4*>(
          &XG[(j * 16 + (lane & 15)) * 72 + wave * 16 + (lane >> 4) * 4]) = gv;
    }
  }
  __syncthreads();  // XG ready; buf reusable
  bf16x8 xgf[2];
#pragma unroll
  for (int ks = 0; ks < 2; ++ks)
    xgf[ks] = *reinterpret_cast<const bf16x8*>(
        &XG[(wave * 16 + (lane & 15)) * 72 + ks * 32 + (lane >> 4) * 8]);
  stage_tile(&WcmB[0], 64, (unsigned short*)buf, wave, lane);
  stage_tile(&x1b[(size_t)b * 65536], 1024, (unsigned short*)(buf + 8192), wave, lane);
  __syncthreads();
  f32x4 accy[4];
#pragma unroll
  for (int j = 0; j < 4; ++j) accy[j] = (f32x4){0.f, 0.f, 0.f, 0.f};
  unsigned short* SB = &SBt[wave * 16 * 72];

  auto chunk_body = [&](const char* base, int ch) {
    const unsigned short* WTcur = (const unsigned short*)base;
    const unsigned short* X1cur = (const unsigned short*)(base + 8192);
#pragma unroll
    for (int i = 0; i < 4; ++i) {
      f32x4 s = (f32x4){0.f, 0.f, 0.f, 0.f};
#pragma unroll
      for (int ks = 0; ks < 2; ++ks) {
        bf16x8 af = fragr(WTcur, i * 16 + (lane & 15), ks, lane);
        s = __builtin_amdgcn_mfma_f32_16x16x32_bf16(af, xgf[ks], s, 0, 0, 0);
      }
      f32x4 bc4 = *reinterpret_cast<const f32x4*>(&bcm[ch * 64 + i * 16 + (lane >> 4) * 4]);
      us4 sv;
#pragma unroll
      for (int r = 0; r < 4; ++r) sv[r] = f2bh(sigmoidf_(s[r] + bc4[r]));
      *reinterpret_cast<us4*>(&SB[(lane & 15) * 72 + i * 16 + (lane >> 4) * 4]) = sv;
    }
#pragma unroll
    for (int ks = 0; ks < 2; ++ks) {
      bf16x8 b2 = *reinterpret_cast<const bf16x8*>(
          &SB[(lane & 15) * 72 + ks * 32 + (lane >> 4) * 8]);
#pragma unroll
      for (int jc = 0; jc < 4; ++jc) {
        bf16x8 a2 = fragr(X1cur, jc * 16 + (lane & 15), ks, lane);
        accy[jc] = __builtin_amdgcn_mfma_f32_16x16x32_bf16(a2, b2, accy[jc], 0, 0, 0);
      }
    }
  };

  for (int hp = 0; hp < 8; ++hp) {
    {  // ch = 2*hp, slot 0; prefetch ch+1 -> slot 1
      const int ch = hp * 2;
      stage_tile(&WcmB[(size_t)(ch + 1) * 4096], 64, (unsigned short*)(buf + 16384), wave, lane);
      stage_tile(&x1b[(size_t)b * 65536 + (ch + 1) * 64], 1024,
                 (unsigned short*)(buf + 16384 + 8192), wave, lane);
      chunk_body(buf, ch);
      __syncthreads();
    }
    {  // ch = 2*hp+1, slot 1; prefetch ch+1 -> slot 0 (if exists)
      const int ch = hp * 2 + 1;
      if (hp < 7) {
        stage_tile(&WcmB[(size_t)(ch + 1) * 4096], 64, (unsigned short*)buf, wave, lane);
        stage_tile(&x1b[(size_t)b * 65536 + (ch + 1) * 64], 1024,
                   (unsigned short*)(buf + 8192), wave, lane);
      }
      chunk_body(buf + 16384, ch);
      __syncthreads();
    }
  }
  // epilogue (wave-private SB reuse): y1 = lrelu(accy) -> YT; out = lrelu(Wdw@y1+bdw)
  unsigned short* YT = SB;
#pragma unroll
  for (int jc = 0; jc < 4; ++jc) {
    us4 yv;
#pragma unroll
    for (int r = 0; r < 4; ++r) yv[r] = f2bh(lrelu(accy[jc][r]));
    *reinterpret_cast<us4*>(&YT[(lane & 15) * 72 + jc * 16 + (lane >> 4) * 4]) = yv;
  }
  bf16x8 afW[4][2];
#pragma unroll
  for (int jo = 0; jo < 4; ++jo)
#pragma unroll
    for (int ks = 0; ks < 2; ++ks)
      afW[jo][ks] = *reinterpret_cast<const bf16x8*>(
          &WdwB[(jo * 16 + (lane & 15)) * 64 + ks * 32 + (lane >> 4) * 8]);
  f32x4 accf[4];
#pragma unroll
  for (int j = 0; j < 4; ++j) accf[j] = (f32x4){0.f, 0.f, 0.f, 0.f};
#pragma unroll
  for (int ks = 0; ks < 2; ++ks) {
    bf16x8 yf = *reinterpret_cast<const bf16x8*>(
        &YT[(lane & 15) * 72 + ks * 32 + (lane >> 4) * 8]);
#pragma unroll
    for (int jo = 0; jo < 4; ++jo)
      accf[jo] = __builtin_amdgcn_mfma_f32_16x16x32_bf16(afW[jo][ks], yf, accf[jo], 0, 0, 0);
  }
#pragma unroll
  for (int jo = 0; jo < 4; ++jo) {
    f32x4 bs4 = *reinterpret_cast<const f32x4*>(&bdw[jo * 16 + (lane >> 4) * 4]);
#pragma unroll
    for (int r = 0; r < 4; ++r) {
      int o = jo * 16 + (lane >> 4) * 4 + r;
      dout[((size_t)(b * 64 + o) << 10) + m0 + wave * 16 + (lane & 15)] =
          lrelu(accf[jo][r] + bs4[r]);
    }
  }
}

extern "C" void kernel_launch(void* const* d_in, const int* in_sizes, int n_in,
                              void* d_out, int out_size, void* d_ws, size_t ws_size,
                              hipStream_t stream) {
  const float* x     = (const float*)d_in[0];
  const float* W_sa  = (const float*)d_in[1];
  const float* W_sw  = (const float*)d_in[2];
  const float* b_sw  = (const float*)d_in[3];
  const float* bn_g  = (const float*)d_in[4];
  const float* bn_b  = (const float*)d_in[5];
  const float* gamma = (const float*)d_in[6];
  const float* W_cm  = (const float*)d_in[7];
  const float* b_cm  = (const float*)d_in[8];
  const float* W_dw  = (const float*)d_in[9];
  const float* b_dw  = (const float*)d_in[10];
  float* out = (float*)d_out;

  char* ws = (char*)d_ws;
  const size_t MB = 1024 * 1024;
  unsigned short* xb     = (unsigned short*)(ws + 0 * MB);    // 4MB
  unsigned short* xbT    = (unsigned short*)(ws + 4 * MB);    // 4MB
  unsigned short* WsaB   = (unsigned short*)(ws + 8 * MB);    // 2MB
  unsigned short* WcmB   = (unsigned short*)(ws + 10 * MB);   // 128KB
  unsigned short* WswB   = (unsigned short*)(ws + 10 * MB + 256 * 1024);  // 8KB
  unsigned short* WdwB   = (unsigned short*)(ws + 10 * MB + 288 * 1024);  // 8KB
  unsigned short* x1b    = (unsigned short*)(ws + 11 * MB);   // 4MB
  float*          en     = (float*)(ws + 15 * MB);            // 512KB
  unsigned short* attB   = (unsigned short*)(ws + 16 * MB);   // 256KB

  prep_kernel<<<1060, 256, 0, stream>>>(x, W_sa, W_cm, W_sw, W_dw, xb, xbT, WsaB, WcmB, WswB,
                                        WdwB);
  k1x1_kernel<<<dim3(16, Bv), 256, 0, stream>>>(xb, WsaB, WswB, x, b_sw, x1b, en);
  bn_att_kernel<<<Cv, 64, 0, stream>>>(en, bn_g, bn_b, attB);
  dynmega_kernel<<<dim3(16, Bv), 256, 0, stream>>>(xbT, x1b, attB, WcmB, WdwB, x, b_cm, b_dw,
                                                   gamma, out);
}